// Round 1
// baseline (2991.768 us; speedup 1.0000x reference)
//
#include <hip/hip_runtime.h>
#include <math.h>

#define HQ 16
#define HKV 2
#define G_REP 8
#define D 128
#define B_SZ 2
#define T_SZ 2048
#define C_SZ 2048

// ---------------------------------------------------------------------------
// Generic fp32 GEMM: C[M,N] = A[M,K] @ B[K,N], row-major. M,N,K multiples of
// 64/64/16. 64x64 tile per 256-thread block, 4x4 per-thread register tile.
// ---------------------------------------------------------------------------
__global__ __launch_bounds__(256) void gemm_f32(
    const float* __restrict__ A, const float* __restrict__ Bm,
    float* __restrict__ Cm, int M, int N, int K)
{
    __shared__ float As[16][68];  // As[k][m]
    __shared__ float Bs[16][68];  // Bs[k][n]
    const int bm = blockIdx.y * 64;
    const int bn = blockIdx.x * 64;
    const int tid = threadIdx.x;
    const int tx = tid & 15, ty = tid >> 4;

    float acc[4][4] = {};

    for (int k0 = 0; k0 < K; k0 += 16) {
        // A tile: 64(m) x 16(k), each thread loads 4 contiguous k's
        {
            int r = tid >> 2;            // 0..63 (m)
            int c4 = (tid & 3) * 4;      // 0..12 (k)
            float4 av = *(const float4*)(A + (size_t)(bm + r) * K + k0 + c4);
            As[c4 + 0][r] = av.x; As[c4 + 1][r] = av.y;
            As[c4 + 2][r] = av.z; As[c4 + 3][r] = av.w;
        }
        // B tile: 16(k) x 64(n)
        {
            int r = tid >> 4;            // 0..15 (k)
            int c4 = (tid & 15) * 4;     // 0..60 (n)
            float4 bv = *(const float4*)(Bm + (size_t)(k0 + r) * N + bn + c4);
            *(float4*)&Bs[r][c4] = bv;
        }
        __syncthreads();
        #pragma unroll
        for (int k = 0; k < 16; ++k) {
            float4 a4 = *(const float4*)&As[k][ty * 4];
            float4 b4 = *(const float4*)&Bs[k][tx * 4];
            float av[4] = {a4.x, a4.y, a4.z, a4.w};
            float bv[4] = {b4.x, b4.y, b4.z, b4.w};
            #pragma unroll
            for (int i = 0; i < 4; ++i)
                #pragma unroll
                for (int j = 0; j < 4; ++j)
                    acc[i][j] += av[i] * bv[j];
        }
        __syncthreads();
    }
    #pragma unroll
    for (int i = 0; i < 4; ++i) {
        float4 v = {acc[i][0], acc[i][1], acc[i][2], acc[i][3]};
        *(float4*)(Cm + (size_t)(bm + ty * 4 + i) * N + bn + tx * 4) = v;
    }
}

// ---------------------------------------------------------------------------
// Gates: Gb[b*T+t][h] = sigmoid( x[b,t,:] @ Wg[:,h] ), h = 0..15.
// One wave per token row.
// ---------------------------------------------------------------------------
__global__ __launch_bounds__(64) void gates_kernel(
    const float* __restrict__ x, const float* __restrict__ Wg,
    float* __restrict__ Gb)
{
    const int t = blockIdx.x;        // 0..B*T-1
    const int lane = threadIdx.x;    // 0..63
    float acc[16] = {};
    const float* xr = x + (size_t)t * C_SZ;
    for (int k = lane; k < C_SZ; k += 64) {
        float xv = xr[k];
        const float4* wr = (const float4*)(Wg + (size_t)k * 16);
        float4 w0 = wr[0], w1 = wr[1], w2 = wr[2], w3 = wr[3];
        acc[0]  += xv * w0.x; acc[1]  += xv * w0.y; acc[2]  += xv * w0.z; acc[3]  += xv * w0.w;
        acc[4]  += xv * w1.x; acc[5]  += xv * w1.y; acc[6]  += xv * w1.z; acc[7]  += xv * w1.w;
        acc[8]  += xv * w2.x; acc[9]  += xv * w2.y; acc[10] += xv * w2.z; acc[11] += xv * w2.w;
        acc[12] += xv * w3.x; acc[13] += xv * w3.y; acc[14] += xv * w3.z; acc[15] += xv * w3.w;
    }
    #pragma unroll
    for (int hh = 0; hh < 16; ++hh) {
        float v = acc[hh];
        v += __shfl_xor(v, 1);  v += __shfl_xor(v, 2);
        v += __shfl_xor(v, 4);  v += __shfl_xor(v, 8);
        v += __shfl_xor(v, 16); v += __shfl_xor(v, 32);
        acc[hh] = 1.0f / (1.0f + __expf(-v));
    }
    if (lane == 0) {
        float* gdst = Gb + (size_t)t * 16;
        float4 g0 = {acc[0],  acc[1],  acc[2],  acc[3]};
        float4 g1 = {acc[4],  acc[5],  acc[6],  acc[7]};
        float4 g2 = {acc[8],  acc[9],  acc[10], acc[11]};
        float4 g3 = {acc[12], acc[13], acc[14], acc[15]};
        *(float4*)(gdst + 0)  = g0; *(float4*)(gdst + 4)  = g1;
        *(float4*)(gdst + 8)  = g2; *(float4*)(gdst + 12) = g3;
    }
}

// ---------------------------------------------------------------------------
// Flash-style causal attention with post-softmax sigmoid gate.
// Grid: (T/64, B*HQ). Block 256 threads. BQ=BK=64.
// Q/K stored transposed in LDS for outer-product S computation.
// ---------------------------------------------------------------------------
#define BQ 64
#define BK 64
#define TPAD 68
#define DPAD 132

__global__ __launch_bounds__(256) void attn_kernel(
    const float* __restrict__ Qb, const float* __restrict__ Kb,
    const float* __restrict__ Vb, const float* __restrict__ Gb,
    float* __restrict__ Ob)
{
    __shared__ float Qst[D][TPAD];   // Qst[d][r]
    __shared__ float Kst[D][TPAD];   // Kst[d][j]
    __shared__ float Vs[BK][DPAD];   // Vs[j][d]
    __shared__ float Pst[BK][TPAD];  // Pst[j][r]

    const int qt  = blockIdx.x;      // 0..T/64-1
    const int bh  = blockIdx.y;      // 0..B*HQ-1
    const int b   = bh >> 4;
    const int h   = bh & 15;
    const int kvh = h >> 3;          // h / G_REP
    const int tid = threadIdx.x;
    const int tx = tid & 15, ty = tid >> 4;

    // Load + transpose Q tile (64 rows x 128 cols)
    {
        const float* qsrc = Qb + ((size_t)(b * T_SZ + qt * BQ)) * (HQ * D) + h * D;
        #pragma unroll
        for (int it = 0; it < 8; ++it) {
            int idx = it * 256 + tid;
            int r = idx >> 5, c4 = idx & 31;
            float4 v = *(const float4*)(qsrc + (size_t)r * (HQ * D) + c4 * 4);
            Qst[c4 * 4 + 0][r] = v.x; Qst[c4 * 4 + 1][r] = v.y;
            Qst[c4 * 4 + 2][r] = v.z; Qst[c4 * 4 + 3][r] = v.w;
        }
    }

    float o[4][8];
    float m_i[4], l_i[4];
    #pragma unroll
    for (int i = 0; i < 4; ++i) {
        m_i[i] = -1e30f; l_i[i] = 0.f;
        #pragma unroll
        for (int c = 0; c < 8; ++c) o[i][c] = 0.f;
    }
    const float scale = 0.08838834764831845f;  // 1/sqrt(128)

    for (int kt = 0; kt <= qt; ++kt) {
        __syncthreads();   // protect Kst/Vs from previous iteration's readers
        const float* ksrc = Kb + ((size_t)(b * T_SZ + kt * BK)) * (HKV * D) + kvh * D;
        const float* vsrc = Vb + ((size_t)(b * T_SZ + kt * BK)) * (HKV * D) + kvh * D;
        #pragma unroll
        for (int it = 0; it < 8; ++it) {
            int idx = it * 256 + tid;
            int r = idx >> 5, c4 = idx & 31;
            float4 kv = *(const float4*)(ksrc + (size_t)r * (HKV * D) + c4 * 4);
            Kst[c4 * 4 + 0][r] = kv.x; Kst[c4 * 4 + 1][r] = kv.y;
            Kst[c4 * 4 + 2][r] = kv.z; Kst[c4 * 4 + 3][r] = kv.w;
            float4 vv = *(const float4*)(vsrc + (size_t)r * (HKV * D) + c4 * 4);
            *(float4*)&Vs[r][c4 * 4] = vv;
        }
        __syncthreads();

        // S = Q K^T (4x4 per thread)
        float s[4][4] = {};
        #pragma unroll 4
        for (int d = 0; d < D; ++d) {
            float4 a4 = *(const float4*)&Qst[d][ty * 4];
            float4 b4 = *(const float4*)&Kst[d][tx * 4];
            float av[4] = {a4.x, a4.y, a4.z, a4.w};
            float bv[4] = {b4.x, b4.y, b4.z, b4.w};
            #pragma unroll
            for (int i = 0; i < 4; ++i)
                #pragma unroll
                for (int j = 0; j < 4; ++j)
                    s[i][j] += av[i] * bv[j];
        }

        // scale + causal mask (diagonal tile only)
        if (kt == qt) {
            #pragma unroll
            for (int i = 0; i < 4; ++i) {
                int gi = ty * 4 + i;
                #pragma unroll
                for (int j = 0; j < 4; ++j) {
                    int gj = tx * 4 + j;
                    s[i][j] = (gj > gi) ? -1e30f : s[i][j] * scale;
                }
            }
        } else {
            #pragma unroll
            for (int i = 0; i < 4; ++i)
                #pragma unroll
                for (int j = 0; j < 4; ++j)
                    s[i][j] *= scale;
        }

        // online softmax: row groups are 16 lanes (same ty), shuffle-reduce
        float alpha[4];
        #pragma unroll
        for (int i = 0; i < 4; ++i) {
            float mx = fmaxf(fmaxf(s[i][0], s[i][1]), fmaxf(s[i][2], s[i][3]));
            mx = fmaxf(mx, __shfl_xor(mx, 1));
            mx = fmaxf(mx, __shfl_xor(mx, 2));
            mx = fmaxf(mx, __shfl_xor(mx, 4));
            mx = fmaxf(mx, __shfl_xor(mx, 8));
            float mnew = fmaxf(m_i[i], mx);
            float rs = 0.f;
            #pragma unroll
            for (int j = 0; j < 4; ++j) { s[i][j] = __expf(s[i][j] - mnew); rs += s[i][j]; }
            rs += __shfl_xor(rs, 1); rs += __shfl_xor(rs, 2);
            rs += __shfl_xor(rs, 4); rs += __shfl_xor(rs, 8);
            alpha[i] = __expf(m_i[i] - mnew);
            l_i[i] = l_i[i] * alpha[i] + rs;
            m_i[i] = mnew;
        }

        // store P transposed (wave-local rows: same ty group writes & reads)
        #pragma unroll
        for (int i = 0; i < 4; ++i)
            #pragma unroll
            for (int j = 0; j < 4; ++j)
                Pst[tx * 4 + j][ty * 4 + i] = s[i][j];

        // rescale O, accumulate P @ V
        #pragma unroll
        for (int i = 0; i < 4; ++i)
            #pragma unroll
            for (int c = 0; c < 8; ++c) o[i][c] *= alpha[i];

        #pragma unroll 2
        for (int j = 0; j < BK; ++j) {
            float4 pq = *(const float4*)&Pst[j][ty * 4];
            float pv[4] = {pq.x, pq.y, pq.z, pq.w};
            float4 v0 = *(const float4*)&Vs[j][tx * 4];
            float4 v1 = *(const float4*)&Vs[j][64 + tx * 4];
            float vv[8] = {v0.x, v0.y, v0.z, v0.w, v1.x, v1.y, v1.z, v1.w};
            #pragma unroll
            for (int i = 0; i < 4; ++i)
                #pragma unroll
                for (int c = 0; c < 8; ++c)
                    o[i][c] += pv[i] * vv[c];
        }
    }

    // epilogue: normalize, gate, store. cols: c<4 -> tx*4+c ; c>=4 -> 64+tx*4+(c-4)
    const float* gsrc = Gb + ((size_t)(b * T_SZ + qt * BQ)) * HQ + h;
    #pragma unroll
    for (int i = 0; i < 4; ++i) {
        int r = ty * 4 + i;
        float g = gsrc[(size_t)r * HQ];
        float inv = g / l_i[i];
        float4 o0 = {o[i][0] * inv, o[i][1] * inv, o[i][2] * inv, o[i][3] * inv};
        float4 o1 = {o[i][4] * inv, o[i][5] * inv, o[i][6] * inv, o[i][7] * inv};
        float* dst = Ob + ((size_t)(b * T_SZ + qt * BQ + r)) * (HQ * D) + h * D;
        *(float4*)(dst + tx * 4) = o0;
        *(float4*)(dst + 64 + tx * 4) = o1;
    }
}

// ---------------------------------------------------------------------------
extern "C" void kernel_launch(void* const* d_in, const int* in_sizes, int n_in,
                              void* d_out, int out_size, void* d_ws, size_t ws_size,
                              hipStream_t stream) {
    const float* x  = (const float*)d_in[0];
    // d_in[1] = mask (ignored: deterministically causal triu(k=1))
    const float* Wq = (const float*)d_in[2];
    const float* Wk = (const float*)d_in[3];
    const float* Wv = (const float*)d_in[4];
    const float* Wo = (const float*)d_in[5];
    const float* Wg = (const float*)d_in[6];
    float* out = (float*)d_out;

    float* ws = (float*)d_ws;
    const size_t BT = (size_t)B_SZ * T_SZ;           // 4096
    float* Qb = ws;                                  // BT * 2048
    float* Kb = Qb + BT * (HQ * D);                  // BT * 256
    float* Vb = Kb + BT * (HKV * D);                 // BT * 256
    float* Gb = Vb + BT * (HKV * D);                 // BT * 16
    float* Ob = Gb + BT * HQ;                        // BT * 2048

    // Q = x @ Wq : (4096 x 2048) @ (2048 x 2048)
    gemm_f32<<<dim3((HQ * D) / 64, BT / 64), 256, 0, stream>>>(x, Wq, Qb, BT, HQ * D, C_SZ);
    // K = x @ Wk : (4096 x 2048) @ (2048 x 256)
    gemm_f32<<<dim3((HKV * D) / 64, BT / 64), 256, 0, stream>>>(x, Wk, Kb, BT, HKV * D, C_SZ);
    // V = x @ Wv
    gemm_f32<<<dim3((HKV * D) / 64, BT / 64), 256, 0, stream>>>(x, Wv, Vb, BT, HKV * D, C_SZ);
    // gates = sigmoid(x @ Wg)
    gates_kernel<<<dim3(BT), 64, 0, stream>>>(x, Wg, Gb);
    // attention
    attn_kernel<<<dim3(T_SZ / BQ, B_SZ * HQ), 256, 0, stream>>>(Qb, Kb, Vb, Gb, Ob);
    // out = Ob @ Wo : (4096 x 2048) @ (2048 x 2048)
    gemm_f32<<<dim3(C_SZ / 64, BT / 64), 256, 0, stream>>>(Ob, Wo, out, BT, C_SZ, C_SZ);
}

// Round 2
// 539.751 us; speedup vs baseline: 5.5429x; 5.5429x over previous
//
#include <hip/hip_runtime.h>
#include <math.h>

#define HQ 16
#define HKV 2
#define D 128
#define B_SZ 2
#define T_SZ 2048
#define C_SZ 2048

typedef __attribute__((ext_vector_type(8))) short short8;
typedef __attribute__((ext_vector_type(4))) float floatx4;

static __device__ __forceinline__ unsigned short f2b(float f) {
    union { float f; unsigned u; } x; x.f = f;
    return (unsigned short)((x.u + 0x7fffu + ((x.u >> 16) & 1u)) >> 16);
}

// async global->LDS, 16B per lane; LDS dst = wave-uniform base + lane*16
static __device__ __forceinline__ void load_lds16(const void* g, void* l) {
    __builtin_amdgcn_global_load_lds(
        (const __attribute__((address_space(1))) void*)g,
        (__attribute__((address_space(3))) void*)l,
        16, 0, 0);
}

// ---------------------------------------------------------------------------
// fp32 -> bf16 elementwise (8 elems/thread)
// ---------------------------------------------------------------------------
__global__ __launch_bounds__(256) void f32_to_bf16_k(
    const float* __restrict__ in, unsigned short* __restrict__ out)
{
    int i = (blockIdx.x * 256 + threadIdx.x) * 8;
    float4 a = *(const float4*)(in + i);
    float4 b = *(const float4*)(in + i + 4);
    ushort4 o0, o1;
    o0.x = f2b(a.x); o0.y = f2b(a.y); o0.z = f2b(a.z); o0.w = f2b(a.w);
    o1.x = f2b(b.x); o1.y = f2b(b.y); o1.z = f2b(b.z); o1.w = f2b(b.w);
    *(ushort4*)(out + i) = o0;
    *(ushort4*)(out + i + 4) = o1;
}

// ---------------------------------------------------------------------------
// W (R,Cc) fp32 row-major -> Wt (Cc,R) bf16 row-major. 32x32 LDS tile.
// grid = (Cc/32, R/32)
// ---------------------------------------------------------------------------
__global__ __launch_bounds__(256) void transpose_f32_bf16(
    const float* __restrict__ in, unsigned short* __restrict__ out, int R, int Cc)
{
    __shared__ float t[32][33];
    const int bc = blockIdx.x * 32, br = blockIdx.y * 32;
    const int tid = threadIdx.x;
    const int r = tid >> 3, c4 = (tid & 7) * 4;
    float4 v = *(const float4*)(in + (size_t)(br + r) * Cc + bc + c4);
    t[r][c4 + 0] = v.x; t[r][c4 + 1] = v.y; t[r][c4 + 2] = v.z; t[r][c4 + 3] = v.w;
    __syncthreads();
    ushort4 o;
    o.x = f2b(t[c4 + 0][r]); o.y = f2b(t[c4 + 1][r]);
    o.z = f2b(t[c4 + 2][r]); o.w = f2b(t[c4 + 3][r]);
    *(ushort4*)(out + (size_t)(bc + r) * R + br + c4) = o;
}

// ---------------------------------------------------------------------------
// bf16 batched transpose: in (Bz, R, Cc) -> out (Bz, Cc, R). grid (Cc/32,R/32,Bz)
// ---------------------------------------------------------------------------
__global__ __launch_bounds__(256) void transpose_bf16(
    const unsigned short* __restrict__ in, unsigned short* __restrict__ out,
    int R, int Cc)
{
    __shared__ unsigned short t[32][36];
    const size_t bo = (size_t)blockIdx.z * R * Cc;
    const int bc = blockIdx.x * 32, br = blockIdx.y * 32;
    const int tid = threadIdx.x;
    const int r = tid >> 3, c4 = (tid & 7) * 4;
    ushort4 v = *(const ushort4*)(in + bo + (size_t)(br + r) * Cc + bc + c4);
    t[r][c4 + 0] = v.x; t[r][c4 + 1] = v.y; t[r][c4 + 2] = v.z; t[r][c4 + 3] = v.w;
    __syncthreads();
    ushort4 o;
    o.x = t[c4 + 0][r]; o.y = t[c4 + 1][r]; o.z = t[c4 + 2][r]; o.w = t[c4 + 3][r];
    *(ushort4*)(out + bo + (size_t)(bc + r) * R + br + c4) = o;
}

// ---------------------------------------------------------------------------
// bf16 MFMA GEMM (m97 structure): C[M,N] = A[M,K] @ Bt[N,K]^T.
// 128x128 tile, 256 thr (2x2 waves, each 64x64 = 4x4 MFMA tiles), BK=32.
// LDS tiles stored as 16B blocks, block pos = cb ^ ((row>>1)&3) so fragment
// ds_read_b128 is 2-way-conflict-free (free per m136).
// ---------------------------------------------------------------------------
__global__ __launch_bounds__(256) void gemm_bt_bf16(
    const unsigned short* __restrict__ A, const unsigned short* __restrict__ Bt,
    float* __restrict__ Cf, unsigned short* __restrict__ Cb,
    int M, int N, int K, int out_bf16)
{
    __shared__ unsigned short As[128 * 32];
    __shared__ unsigned short Bs[128 * 32];
    const int tid = threadIdx.x;
    const int lane = tid & 63, wave = tid >> 6;
    const int l15 = lane & 15, quad = lane >> 4;
    const int wr = wave >> 1, wc = wave & 1;
    const int bm = blockIdx.y * 128, bn = blockIdx.x * 128;

    floatx4 zero = {0.f, 0.f, 0.f, 0.f};
    floatx4 acc[4][4];
    #pragma unroll
    for (int i = 0; i < 4; ++i)
        #pragma unroll
        for (int j = 0; j < 4; ++j) acc[i][j] = zero;

    // staging decomposition: lds block idx = it*256 + tid; row=idx/4, sb=idx%4
    int arow[2], acol[2];
    #pragma unroll
    for (int it = 0; it < 2; ++it) {
        int idx = it * 256 + tid;
        int row = idx >> 2, sb = idx & 3;
        int cb = sb ^ ((row >> 1) & 3);
        arow[it] = row; acol[it] = cb * 8;
    }
    const int sw = quad ^ ((l15 >> 1) & 3);  // fragment-read swizzle

    for (int k0 = 0; k0 < K; k0 += 32) {
        __syncthreads();
        #pragma unroll
        for (int it = 0; it < 2; ++it) {
            load_lds16(A  + (size_t)(bm + arow[it]) * K + k0 + acol[it],
                       &As[(it * 256 + wave * 64) * 8]);
            load_lds16(Bt + (size_t)(bn + arow[it]) * K + k0 + acol[it],
                       &Bs[(it * 256 + wave * 64) * 8]);
        }
        __syncthreads();

        short8 af[4], bf[4];
        #pragma unroll
        for (int mt = 0; mt < 4; ++mt)
            af[mt] = *(const short8*)&As[((wr * 64 + mt * 16 + l15) * 4 + sw) * 8];
        #pragma unroll
        for (int nt = 0; nt < 4; ++nt)
            bf[nt] = *(const short8*)&Bs[((wc * 64 + nt * 16 + l15) * 4 + sw) * 8];
        #pragma unroll
        for (int mt = 0; mt < 4; ++mt)
            #pragma unroll
            for (int nt = 0; nt < 4; ++nt)
                acc[mt][nt] = __builtin_amdgcn_mfma_f32_16x16x32_bf16(
                    af[mt], bf[nt], acc[mt][nt], 0, 0, 0);
    }

    #pragma unroll
    for (int mt = 0; mt < 4; ++mt)
        #pragma unroll
        for (int nt = 0; nt < 4; ++nt)
            #pragma unroll
            for (int r = 0; r < 4; ++r) {
                int m = bm + wr * 64 + mt * 16 + quad * 4 + r;
                int n = bn + wc * 64 + nt * 16 + l15;
                if (out_bf16) Cb[(size_t)m * N + n] = f2b(acc[mt][nt][r]);
                else          Cf[(size_t)m * N + n] = acc[mt][nt][r];
            }
}

// ---------------------------------------------------------------------------
// Gates: Gb[t][h] = sigmoid(x[t,:] @ Wg[:,h]). One wave per token (fp32).
// ---------------------------------------------------------------------------
__global__ __launch_bounds__(64) void gates_kernel(
    const float* __restrict__ x, const float* __restrict__ Wg,
    float* __restrict__ Gb)
{
    const int t = blockIdx.x;
    const int lane = threadIdx.x;
    float acc[16] = {};
    const float* xr = x + (size_t)t * C_SZ;
    for (int k = lane; k < C_SZ; k += 64) {
        float xv = xr[k];
        const float4* wr = (const float4*)(Wg + (size_t)k * 16);
        float4 w0 = wr[0], w1 = wr[1], w2 = wr[2], w3 = wr[3];
        acc[0]  += xv * w0.x; acc[1]  += xv * w0.y; acc[2]  += xv * w0.z; acc[3]  += xv * w0.w;
        acc[4]  += xv * w1.x; acc[5]  += xv * w1.y; acc[6]  += xv * w1.z; acc[7]  += xv * w1.w;
        acc[8]  += xv * w2.x; acc[9]  += xv * w2.y; acc[10] += xv * w2.z; acc[11] += xv * w2.w;
        acc[12] += xv * w3.x; acc[13] += xv * w3.y; acc[14] += xv * w3.z; acc[15] += xv * w3.w;
    }
    #pragma unroll
    for (int hh = 0; hh < 16; ++hh) {
        float v = acc[hh];
        v += __shfl_xor(v, 1);  v += __shfl_xor(v, 2);
        v += __shfl_xor(v, 4);  v += __shfl_xor(v, 8);
        v += __shfl_xor(v, 16); v += __shfl_xor(v, 32);
        acc[hh] = 1.0f / (1.0f + __expf(-v));
    }
    if (lane == 0) {
        float* gd = Gb + (size_t)t * 16;
        float4 g0 = {acc[0], acc[1], acc[2],  acc[3]};
        float4 g1 = {acc[4], acc[5], acc[6],  acc[7]};
        float4 g2 = {acc[8], acc[9], acc[10], acc[11]};
        float4 g3 = {acc[12], acc[13], acc[14], acc[15]};
        *(float4*)(gd + 0) = g0; *(float4*)(gd + 4)  = g1;
        *(float4*)(gd + 8) = g2; *(float4*)(gd + 12) = g3;
    }
}

// ---------------------------------------------------------------------------
// MFMA flash attention, BQ=BK=64, 4 waves (wave w owns q-rows [w*16,w*16+16)).
// Q in regs; K tile and V^T tile staged via global_load_lds with XOR-swizzled
// 16B blocks; P goes C-layout -> LDS(bf16, stride 72) -> A-layout (m120).
// Output written as bf16 (feeds O-projection GEMM). Gate fused in epilogue.
// ---------------------------------------------------------------------------
__global__ __launch_bounds__(256) void attn_mfma(
    const unsigned short* __restrict__ Qb, const unsigned short* __restrict__ Kb,
    const unsigned short* __restrict__ Vt, const float* __restrict__ Gb,
    unsigned short* __restrict__ Ob)
{
    __shared__ unsigned short Ks[64 * 128];   // [key][d], swizzled blocks
    __shared__ unsigned short Vs[128 * 64];   // [d][key], swizzled blocks
    __shared__ unsigned short Ps[4 * 16 * 72];

    const int qt = blockIdx.x, bh = blockIdx.y;
    const int b = bh >> 4, h = bh & 15, kvh = h >> 3;
    const int tid = threadIdx.x;
    const int lane = tid & 63, w = tid >> 6;
    const int l15 = lane & 15, quad = lane >> 4;

    // Q fragments (fixed for whole kernel): rows w*16+l15, k = kd*32+quad*8+j
    short8 aq[4];
    {
        const unsigned short* qp = Qb + (size_t)(b * T_SZ + qt * 64 + w * 16 + l15) * (HQ * D)
                                      + h * D + quad * 8;
        #pragma unroll
        for (int kd = 0; kd < 4; ++kd) aq[kd] = *(const short8*)(qp + kd * 32);
    }

    // staging pointers (kt=0); advance per iteration
    const unsigned short* kg[4];
    const unsigned short* vg[4];
    #pragma unroll
    for (int it = 0; it < 4; ++it) {
        int Bi = it * 256 + tid;
        int kr = Bi >> 4, kc = ((Bi & 15) ^ (kr & 15)) * 8;
        kg[it] = Kb + (size_t)(b * T_SZ + kr) * (HKV * D) + kvh * D + kc;
        int vr = Bi >> 3, vc = ((Bi & 7) ^ (vr & 7)) * 8;
        vg[it] = Vt + (size_t)((b * HKV + kvh) * D + vr) * T_SZ + vc;
    }

    floatx4 zero = {0.f, 0.f, 0.f, 0.f};
    floatx4 oacc[8];
    #pragma unroll
    for (int dt = 0; dt < 8; ++dt) oacc[dt] = zero;
    float m_i[4] = {-1e30f, -1e30f, -1e30f, -1e30f};
    float l_i[4] = {0.f, 0.f, 0.f, 0.f};
    const float scale = 0.08838834764831845f;  // 1/sqrt(128)

    for (int kt = 0; kt <= qt; ++kt) {
        __syncthreads();
        #pragma unroll
        for (int it = 0; it < 4; ++it) {
            load_lds16(kg[it] + (size_t)kt * 64 * (HKV * D), &Ks[(it * 256 + w * 64) * 8]);
            load_lds16(vg[it] + kt * 64,                     &Vs[(it * 256 + w * 64) * 8]);
        }
        __syncthreads();

        // S = Q K^T : 4 key-tiles x 4 d-ksteps
        floatx4 sacc[4];
        #pragma unroll
        for (int nt = 0; nt < 4; ++nt) sacc[nt] = zero;
        #pragma unroll
        for (int kd = 0; kd < 4; ++kd)
            #pragma unroll
            for (int nt = 0; nt < 4; ++nt) {
                short8 bk = *(const short8*)&Ks[((nt * 16 + l15) * 16 + ((kd * 4 + quad) ^ l15)) * 8];
                sacc[nt] = __builtin_amdgcn_mfma_f32_16x16x32_bf16(aq[kd], bk, sacc[nt], 0, 0, 0);
            }

        float s[4][4];
        #pragma unroll
        for (int nt = 0; nt < 4; ++nt)
            #pragma unroll
            for (int r = 0; r < 4; ++r) s[nt][r] = sacc[nt][r] * scale;

        if (kt == qt) {  // causal mask on diagonal tile
            #pragma unroll
            for (int nt = 0; nt < 4; ++nt) {
                int col = nt * 16 + l15;
                #pragma unroll
                for (int r = 0; r < 4; ++r)
                    if (col > w * 16 + quad * 4 + r) s[nt][r] = -1e30f;
            }
        }

        // online softmax per row (rows live on 16 lanes of a quad)
        float alpha[4];
        #pragma unroll
        for (int r = 0; r < 4; ++r) {
            float mx = fmaxf(fmaxf(s[0][r], s[1][r]), fmaxf(s[2][r], s[3][r]));
            mx = fmaxf(mx, __shfl_xor(mx, 1));
            mx = fmaxf(mx, __shfl_xor(mx, 2));
            mx = fmaxf(mx, __shfl_xor(mx, 4));
            mx = fmaxf(mx, __shfl_xor(mx, 8));
            float mnew = fmaxf(m_i[r], mx);
            float rs = 0.f;
            #pragma unroll
            for (int nt = 0; nt < 4; ++nt) { s[nt][r] = __expf(s[nt][r] - mnew); rs += s[nt][r]; }
            rs += __shfl_xor(rs, 1); rs += __shfl_xor(rs, 2);
            rs += __shfl_xor(rs, 4); rs += __shfl_xor(rs, 8);
            alpha[r] = __expf(m_i[r] - mnew);
            l_i[r] = l_i[r] * alpha[r] + rs;
            m_i[r] = mnew;
        }

        // P: C-layout -> LDS (bf16), wave-private region, stride 72 (pad)
        #pragma unroll
        for (int nt = 0; nt < 4; ++nt)
            #pragma unroll
            for (int r = 0; r < 4; ++r)
                Ps[(w * 16 + quad * 4 + r) * 72 + nt * 16 + l15] = f2b(s[nt][r]);

        // rescale O
        #pragma unroll
        for (int dt = 0; dt < 8; ++dt)
            #pragma unroll
            for (int r = 0; r < 4; ++r) oacc[dt][r] *= alpha[r];

        // O += P V  (A-frag from Ps; B-frag from swizzled V^T tile)
        #pragma unroll
        for (int kk = 0; kk < 2; ++kk) {
            short8 ap = *(const short8*)&Ps[(w * 16 + l15) * 72 + kk * 32 + quad * 8];
            #pragma unroll
            for (int dt = 0; dt < 8; ++dt) {
                short8 bv = *(const short8*)&Vs[((dt * 16 + l15) * 8 + ((kk * 4 + quad) ^ (l15 & 7))) * 8];
                oacc[dt] = __builtin_amdgcn_mfma_f32_16x16x32_bf16(ap, bv, oacc[dt], 0, 0, 0);
            }
        }
    }

    // epilogue: normalize + gate, store bf16
    #pragma unroll
    for (int r = 0; r < 4; ++r) {
        int trow = b * T_SZ + qt * 64 + w * 16 + quad * 4 + r;
        float g = Gb[(size_t)trow * HQ + h];
        float f = g / l_i[r];
        unsigned short* op = Ob + (size_t)trow * (HQ * D) + h * D + l15;
        #pragma unroll
        for (int dt = 0; dt < 8; ++dt) op[dt * 16] = f2b(oacc[dt][r] * f);
    }
}

// ---------------------------------------------------------------------------
extern "C" void kernel_launch(void* const* d_in, const int* in_sizes, int n_in,
                              void* d_out, int out_size, void* d_ws, size_t ws_size,
                              hipStream_t stream) {
    const float* x  = (const float*)d_in[0];
    // d_in[1] = mask (deterministically causal; ignored)
    const float* Wq = (const float*)d_in[2];
    const float* Wk = (const float*)d_in[3];
    const float* Wv = (const float*)d_in[4];
    const float* Wo = (const float*)d_in[5];
    const float* Wg = (const float*)d_in[6];
    float* out = (float*)d_out;

    const size_t MB = 1ull << 20;
    char* p = (char*)d_ws;
    unsigned short* xb  = (unsigned short*)(p);            // 16 MB (dead after V-proj)
    unsigned short* Ob  = xb;                              // alias: attn out (bf16)
    unsigned short* Wqt = (unsigned short*)(p + 16 * MB);  // 8 MB
    unsigned short* Wkt = (unsigned short*)(p + 24 * MB);  // 1 MB
    unsigned short* Wvt = (unsigned short*)(p + 25 * MB);  // 1 MB
    unsigned short* Wot = (unsigned short*)(p + 26 * MB);  // 8 MB
    unsigned short* Qb  = (unsigned short*)(p + 34 * MB);  // 16 MB
    unsigned short* Kb  = (unsigned short*)(p + 50 * MB);  // 2 MB
    unsigned short* Vb  = (unsigned short*)(p + 52 * MB);  // 2 MB
    unsigned short* Vt  = (unsigned short*)(p + 54 * MB);  // 2 MB
    float*          Gb  = (float*)(p + 56 * MB);           // 256 KB
    const int BT = B_SZ * T_SZ;  // 4096

    // bf16 casts / weight transposes
    f32_to_bf16_k<<<dim3(BT * C_SZ / 2048), 256, 0, stream>>>(x, xb);
    transpose_f32_bf16<<<dim3(64, 64), 256, 0, stream>>>(Wq, Wqt, C_SZ, HQ * D);
    transpose_f32_bf16<<<dim3(8, 64), 256, 0, stream>>>(Wk, Wkt, C_SZ, HKV * D);
    transpose_f32_bf16<<<dim3(8, 64), 256, 0, stream>>>(Wv, Wvt, C_SZ, HKV * D);
    transpose_f32_bf16<<<dim3(64, 64), 256, 0, stream>>>(Wo, Wot, HQ * D, C_SZ);

    // projections (bf16 out)
    gemm_bt_bf16<<<dim3((HQ * D) / 128, BT / 128), 256, 0, stream>>>(
        xb, Wqt, nullptr, Qb, BT, HQ * D, C_SZ, 1);
    gemm_bt_bf16<<<dim3((HKV * D) / 128, BT / 128), 256, 0, stream>>>(
        xb, Wkt, nullptr, Kb, BT, HKV * D, C_SZ, 1);
    gemm_bt_bf16<<<dim3((HKV * D) / 128, BT / 128), 256, 0, stream>>>(
        xb, Wvt, nullptr, Vb, BT, HKV * D, C_SZ, 1);

    // V^T per batch: (T,256) -> (256,T)
    transpose_bf16<<<dim3((HKV * D) / 32, T_SZ / 32, B_SZ), 256, 0, stream>>>(
        Vb, Vt, T_SZ, HKV * D);

    gates_kernel<<<dim3(BT), 64, 0, stream>>>(x, Wg, Gb);

    attn_mfma<<<dim3(T_SZ / 64, B_SZ * HQ), 256, 0, stream>>>(Qb, Kb, Vt, Gb, Ob);

    // out = Ob @ Wo (fp32 out)
    gemm_bt_bf16<<<dim3(C_SZ / 128, BT / 128), 256, 0, stream>>>(
        Ob, Wot, out, nullptr, BT, C_SZ, HQ * D, 0);
}

// Round 3
// 364.655 us; speedup vs baseline: 8.2044x; 1.4802x over previous
//
#include <hip/hip_runtime.h>
#include <math.h>

#define HQ 16
#define HKV 2
#define D 128
#define B_SZ 2
#define T_SZ 2048
#define C_SZ 2048
#define QKVN 2560   // HQ*D + 2*HKV*D

typedef __attribute__((ext_vector_type(8))) short short8;
typedef __attribute__((ext_vector_type(4))) float floatx4;

static __device__ __forceinline__ unsigned short f2b(float f) {
    union { float f; unsigned u; } x; x.f = f;
    return (unsigned short)((x.u + 0x7fffu + ((x.u >> 16) & 1u)) >> 16);
}

// async global->LDS, 16B per lane; LDS dst = wave-uniform base + lane*16
static __device__ __forceinline__ void load_lds16(const void* g, void* l) {
    __builtin_amdgcn_global_load_lds(
        (const __attribute__((address_space(1))) void*)g,
        (__attribute__((address_space(3))) void*)l,
        16, 0, 0);
}

// ---------------------------------------------------------------------------
__global__ __launch_bounds__(256) void f32_to_bf16_k(
    const float* __restrict__ in, unsigned short* __restrict__ out)
{
    int i = (blockIdx.x * 256 + threadIdx.x) * 8;
    float4 a = *(const float4*)(in + i);
    float4 b = *(const float4*)(in + i + 4);
    ushort4 o0, o1;
    o0.x = f2b(a.x); o0.y = f2b(a.y); o0.z = f2b(a.z); o0.w = f2b(a.w);
    o1.x = f2b(b.x); o1.y = f2b(b.y); o1.z = f2b(b.z); o1.w = f2b(b.w);
    *(ushort4*)(out + i) = o0;
    *(ushort4*)(out + i + 4) = o1;
}

// ---------------------------------------------------------------------------
// W (R,Cc) fp32 row-major -> Wt (Cc,R) bf16 row-major. grid (Cc/32, R/32)
// ---------------------------------------------------------------------------
__global__ __launch_bounds__(256) void transpose_f32_bf16(
    const float* __restrict__ in, unsigned short* __restrict__ out, int R, int Cc)
{
    __shared__ float t[32][33];
    const int bc = blockIdx.x * 32, br = blockIdx.y * 32;
    const int tid = threadIdx.x;
    const int r = tid >> 3, c4 = (tid & 7) * 4;
    float4 v = *(const float4*)(in + (size_t)(br + r) * Cc + bc + c4);
    t[r][c4 + 0] = v.x; t[r][c4 + 1] = v.y; t[r][c4 + 2] = v.z; t[r][c4 + 3] = v.w;
    __syncthreads();
    ushort4 o;
    o.x = f2b(t[c4 + 0][r]); o.y = f2b(t[c4 + 1][r]);
    o.z = f2b(t[c4 + 2][r]); o.w = f2b(t[c4 + 3][r]);
    *(ushort4*)(out + (size_t)(bc + r) * R + br + c4) = o;
}

// ---------------------------------------------------------------------------
// Strided bf16 transpose (for V inside fused QKV): in (bz, R, Cc) with row
// stride istr -> out (bz, Cc, R). grid (Cc/32, R/32, bz)
// ---------------------------------------------------------------------------
__global__ __launch_bounds__(256) void transpose_bf16_str(
    const unsigned short* __restrict__ in, unsigned short* __restrict__ out,
    int R, int Cc, int istr, long long ibstr, long long obstr)
{
    __shared__ unsigned short t[32][36];
    const int bz = blockIdx.z;
    const int bc = blockIdx.x * 32, br = blockIdx.y * 32;
    const int tid = threadIdx.x;
    const int r = tid >> 3, c4 = (tid & 7) * 4;
    ushort4 v = *(const ushort4*)(in + (size_t)bz * ibstr + (size_t)(br + r) * istr + bc + c4);
    t[r][c4 + 0] = v.x; t[r][c4 + 1] = v.y; t[r][c4 + 2] = v.z; t[r][c4 + 3] = v.w;
    __syncthreads();
    ushort4 o;
    o.x = t[c4 + 0][r]; o.y = t[c4 + 1][r]; o.z = t[c4 + 2][r]; o.w = t[c4 + 3][r];
    *(ushort4*)(out + (size_t)bz * obstr + (size_t)(bc + r) * R + br + c4) = o;
}

// ---------------------------------------------------------------------------
// bf16 MFMA GEMM (m97 structure): C[M,N] = A[M,K] @ Bt[N,K]^T.
// 128x128 tile, 256 thr, BK=32, XOR-swizzled 16B LDS blocks.
// ---------------------------------------------------------------------------
__global__ __launch_bounds__(256) void gemm_bt_bf16(
    const unsigned short* __restrict__ A, const unsigned short* __restrict__ Bt,
    float* __restrict__ Cf, unsigned short* __restrict__ Cb,
    int M, int N, int K, int out_bf16)
{
    __shared__ unsigned short As[128 * 32];
    __shared__ unsigned short Bs[128 * 32];
    const int tid = threadIdx.x;
    const int lane = tid & 63, wave = tid >> 6;
    const int l15 = lane & 15, quad = lane >> 4;
    const int wr = wave >> 1, wc = wave & 1;
    const int bm = blockIdx.y * 128, bn = blockIdx.x * 128;

    floatx4 zero = {0.f, 0.f, 0.f, 0.f};
    floatx4 acc[4][4];
    #pragma unroll
    for (int i = 0; i < 4; ++i)
        #pragma unroll
        for (int j = 0; j < 4; ++j) acc[i][j] = zero;

    int arow[2], acol[2];
    #pragma unroll
    for (int it = 0; it < 2; ++it) {
        int idx = it * 256 + tid;
        int row = idx >> 2, sb = idx & 3;
        int cb = sb ^ ((row >> 1) & 3);
        arow[it] = row; acol[it] = cb * 8;
    }
    const int sw = quad ^ ((l15 >> 1) & 3);

    for (int k0 = 0; k0 < K; k0 += 32) {
        __syncthreads();
        #pragma unroll
        for (int it = 0; it < 2; ++it) {
            load_lds16(A  + (size_t)(bm + arow[it]) * K + k0 + acol[it],
                       &As[(it * 256 + wave * 64) * 8]);
            load_lds16(Bt + (size_t)(bn + arow[it]) * K + k0 + acol[it],
                       &Bs[(it * 256 + wave * 64) * 8]);
        }
        __syncthreads();

        short8 af[4], bf[4];
        #pragma unroll
        for (int mt = 0; mt < 4; ++mt)
            af[mt] = *(const short8*)&As[((wr * 64 + mt * 16 + l15) * 4 + sw) * 8];
        #pragma unroll
        for (int nt = 0; nt < 4; ++nt)
            bf[nt] = *(const short8*)&Bs[((wc * 64 + nt * 16 + l15) * 4 + sw) * 8];
        #pragma unroll
        for (int mt = 0; mt < 4; ++mt)
            #pragma unroll
            for (int nt = 0; nt < 4; ++nt)
                acc[mt][nt] = __builtin_amdgcn_mfma_f32_16x16x32_bf16(
                    af[mt], bf[nt], acc[mt][nt], 0, 0, 0);
    }

    #pragma unroll
    for (int mt = 0; mt < 4; ++mt)
        #pragma unroll
        for (int nt = 0; nt < 4; ++nt)
            #pragma unroll
            for (int r = 0; r < 4; ++r) {
                int m = bm + wr * 64 + mt * 16 + quad * 4 + r;
                int n = bn + wc * 64 + nt * 16 + l15;
                if (out_bf16) Cb[(size_t)m * N + n] = f2b(acc[mt][nt][r]);
                else          Cf[(size_t)m * N + n] = acc[mt][nt][r];
            }
}

// ---------------------------------------------------------------------------
// Gates: Gb[t][h] = sigmoid(x[t,:] @ Wg[:,h]). One wave per token (fp32).
// ---------------------------------------------------------------------------
__global__ __launch_bounds__(64) void gates_kernel(
    const float* __restrict__ x, const float* __restrict__ Wg,
    float* __restrict__ Gb)
{
    const int t = blockIdx.x;
    const int lane = threadIdx.x;
    float acc[16] = {};
    const float* xr = x + (size_t)t * C_SZ;
    for (int k = lane; k < C_SZ; k += 64) {
        float xv = xr[k];
        const float4* wr = (const float4*)(Wg + (size_t)k * 16);
        float4 w0 = wr[0], w1 = wr[1], w2 = wr[2], w3 = wr[3];
        acc[0]  += xv * w0.x; acc[1]  += xv * w0.y; acc[2]  += xv * w0.z; acc[3]  += xv * w0.w;
        acc[4]  += xv * w1.x; acc[5]  += xv * w1.y; acc[6]  += xv * w1.z; acc[7]  += xv * w1.w;
        acc[8]  += xv * w2.x; acc[9]  += xv * w2.y; acc[10] += xv * w2.z; acc[11] += xv * w2.w;
        acc[12] += xv * w3.x; acc[13] += xv * w3.y; acc[14] += xv * w3.z; acc[15] += xv * w3.w;
    }
    #pragma unroll
    for (int hh = 0; hh < 16; ++hh) {
        float v = acc[hh];
        v += __shfl_xor(v, 1);  v += __shfl_xor(v, 2);
        v += __shfl_xor(v, 4);  v += __shfl_xor(v, 8);
        v += __shfl_xor(v, 16); v += __shfl_xor(v, 32);
        acc[hh] = 1.0f / (1.0f + __expf(-v));
    }
    if (lane == 0) {
        float* gd = Gb + (size_t)t * 16;
        float4 g0 = {acc[0], acc[1], acc[2],  acc[3]};
        float4 g1 = {acc[4], acc[5], acc[6],  acc[7]};
        float4 g2 = {acc[8], acc[9], acc[10], acc[11]};
        float4 g3 = {acc[12], acc[13], acc[14], acc[15]};
        *(float4*)(gd + 0) = g0; *(float4*)(gd + 4)  = g1;
        *(float4*)(gd + 8) = g2; *(float4*)(gd + 12) = g3;
    }
}

// ---------------------------------------------------------------------------
// MFMA flash attention, TRANSPOSED orientation: S^T = K Q^T, O^T = V^T P^T.
// Each lane owns one q column (q = w*16 + l15): softmax state is lane-scalar,
// reductions are 16 in-lane ops + 2 shuffles. P^T repack: 4x ds_write_b64 to
// q-major Ps, PV B-frag read = 2x ds_read_b128. O^T transposed back via LDS.
// Grid (B*HQ, T/64); qt reversed for load balance (long blocks first).
// ---------------------------------------------------------------------------
__global__ __launch_bounds__(256) void attn_mfma(
    const unsigned short* __restrict__ QKV, const unsigned short* __restrict__ Vt,
    const float* __restrict__ Gb, unsigned short* __restrict__ Ob)
{
    __shared__ __align__(16) unsigned short SMEM[64 * 128 + 128 * 64 + 4 * 16 * 72];
    unsigned short* Ks = SMEM;                        // [key][d] swizzled 16B blocks
    unsigned short* Vs = SMEM + 64 * 128;             // [d][key] swizzled
    unsigned short* Ps = SMEM + 64 * 128 + 128 * 64;  // [wave][q=16][72]
    unsigned short* Lo = SMEM;                        // epilogue [64][136] (aliases Ks/Vs)

    const int bh = blockIdx.x;
    const int qt = (int)gridDim.y - 1 - (int)blockIdx.y;  // long blocks dispatch first
    const int b = bh >> 4, h = bh & 15, kvh = h >> 3;
    const int tid = threadIdx.x;
    const int lane = tid & 63, w = tid >> 6;
    const int l15 = lane & 15, quad = lane >> 4;
    const int q_local = w * 16 + l15;

    // Q fragments (B-operand): q row = qt*64 + q_local, k = kd*32 + quad*8 + j
    short8 aq[4];
    {
        const unsigned short* qp = QKV + (size_t)(b * T_SZ + qt * 64 + q_local) * QKVN
                                       + h * D + quad * 8;
        #pragma unroll
        for (int kd = 0; kd < 4; ++kd) aq[kd] = *(const short8*)(qp + kd * 32);
    }

    // staging pointers (kt=0)
    const unsigned short* kg[4];
    const unsigned short* vg[4];
    #pragma unroll
    for (int it = 0; it < 4; ++it) {
        int Bi = it * 256 + tid;
        int kr = Bi >> 4, kc = ((Bi & 15) ^ (kr & 15)) * 8;
        kg[it] = QKV + (size_t)(b * T_SZ + kr) * QKVN + HQ * D + kvh * D + kc;
        int vr = Bi >> 3, vc = ((Bi & 7) ^ (vr & 7)) * 8;
        vg[it] = Vt + (size_t)((b * HKV + kvh) * D + vr) * T_SZ + vc;
    }

    floatx4 zero = {0.f, 0.f, 0.f, 0.f};
    floatx4 oacc[8];   // O^T tiles: row=d (dt*16+quad*4+r), col=q (l15)
    #pragma unroll
    for (int dt = 0; dt < 8; ++dt) oacc[dt] = zero;
    float m_i = -1e30f, l_i = 0.f;
    const float scale = 0.08838834764831845f;  // 1/sqrt(128)

    for (int kt = 0; kt <= qt; ++kt) {
        __syncthreads();
        #pragma unroll
        for (int it = 0; it < 4; ++it) {
            load_lds16(kg[it] + (size_t)kt * 64 * QKVN, &Ks[(it * 256 + w * 64) * 8]);
            load_lds16(vg[it] + kt * 64,                &Vs[(it * 256 + w * 64) * 8]);
        }
        __syncthreads();

        // S^T = K Q^T : row=key (4 tiles), col=q
        floatx4 sacc[4];
        #pragma unroll
        for (int nt = 0; nt < 4; ++nt) sacc[nt] = zero;
        #pragma unroll
        for (int kd = 0; kd < 4; ++kd)
            #pragma unroll
            for (int nt = 0; nt < 4; ++nt) {
                short8 ak = *(const short8*)&Ks[((nt * 16 + l15) * 16 + ((kd * 4 + quad) ^ l15)) * 8];
                sacc[nt] = __builtin_amdgcn_mfma_f32_16x16x32_bf16(ak, aq[kd], sacc[nt], 0, 0, 0);
            }

        float s[4][4];
        #pragma unroll
        for (int nt = 0; nt < 4; ++nt)
            #pragma unroll
            for (int r = 0; r < 4; ++r) s[nt][r] = sacc[nt][r] * scale;

        if (kt == qt) {  // causal: key_local > q_local
            #pragma unroll
            for (int nt = 0; nt < 4; ++nt)
                #pragma unroll
                for (int r = 0; r < 4; ++r)
                    if (nt * 16 + quad * 4 + r > q_local) s[nt][r] = -1e30f;
        }

        // lane-scalar online softmax (q fixed per lane; keys split across quads)
        float mx = s[0][0];
        #pragma unroll
        for (int nt = 0; nt < 4; ++nt)
            #pragma unroll
            for (int r = 0; r < 4; ++r) mx = fmaxf(mx, s[nt][r]);
        mx = fmaxf(mx, __shfl_xor(mx, 16));
        mx = fmaxf(mx, __shfl_xor(mx, 32));
        float mnew = fmaxf(m_i, mx);
        float rs = 0.f;
        #pragma unroll
        for (int nt = 0; nt < 4; ++nt)
            #pragma unroll
            for (int r = 0; r < 4; ++r) { s[nt][r] = __expf(s[nt][r] - mnew); rs += s[nt][r]; }
        rs += __shfl_xor(rs, 16);
        rs += __shfl_xor(rs, 32);
        float alpha = __expf(m_i - mnew);
        l_i = l_i * alpha + rs;
        m_i = mnew;

        // P^T -> q-major LDS: Ps[wave][q=l15][key], 4 keys packed per write
        #pragma unroll
        for (int nt = 0; nt < 4; ++nt) {
            ushort4 pk;
            pk.x = f2b(s[nt][0]); pk.y = f2b(s[nt][1]);
            pk.z = f2b(s[nt][2]); pk.w = f2b(s[nt][3]);
            *(ushort4*)&Ps[(w * 16 + l15) * 72 + nt * 16 + quad * 4] = pk;
        }

        // rescale O^T by lane-scalar alpha
        #pragma unroll
        for (int dt = 0; dt < 8; ++dt)
            #pragma unroll
            for (int r = 0; r < 4; ++r) oacc[dt][r] *= alpha;

        // O^T += V^T P^T : A = V^T frag (m=d), B = P^T frag (n=q)
        #pragma unroll
        for (int kk = 0; kk < 2; ++kk) {
            short8 bp = *(const short8*)&Ps[(w * 16 + l15) * 72 + kk * 32 + quad * 8];
            #pragma unroll
            for (int dt = 0; dt < 8; ++dt) {
                short8 av = *(const short8*)&Vs[((dt * 16 + l15) * 8 + ((kk * 4 + quad) ^ (l15 & 7))) * 8];
                oacc[dt] = __builtin_amdgcn_mfma_f32_16x16x32_bf16(av, bp, oacc[dt], 0, 0, 0);
            }
        }
    }

    // epilogue: gate+normalize (lane-scalar), transpose O^T -> O via LDS
    __syncthreads();   // Ks/Vs dead everywhere before Lo overwrite
    {
        int token = b * T_SZ + qt * 64 + q_local;
        float g = Gb[(size_t)token * HQ + h];
        float f = g / l_i;
        #pragma unroll
        for (int dt = 0; dt < 8; ++dt) {
            ushort4 ov;
            ov.x = f2b(oacc[dt][0] * f); ov.y = f2b(oacc[dt][1] * f);
            ov.z = f2b(oacc[dt][2] * f); ov.w = f2b(oacc[dt][3] * f);
            *(ushort4*)&Lo[(size_t)q_local * 136 + dt * 16 + quad * 4] = ov;
        }
    }
    __syncthreads();
    {
        int row = tid >> 2, c0 = (tid & 3) * 32;
        size_t tok = (size_t)(b * T_SZ + qt * 64 + row);
        unsigned short* op = Ob + tok * (HQ * D) + h * D + c0;
        const unsigned short* lp = &Lo[(size_t)row * 136 + c0];
        short8 v0 = *(const short8*)(lp + 0);
        short8 v1 = *(const short8*)(lp + 8);
        short8 v2 = *(const short8*)(lp + 16);
        short8 v3 = *(const short8*)(lp + 24);
        *(short8*)(op + 0)  = v0; *(short8*)(op + 8)  = v1;
        *(short8*)(op + 16) = v2; *(short8*)(op + 24) = v3;
    }
}

// ---------------------------------------------------------------------------
extern "C" void kernel_launch(void* const* d_in, const int* in_sizes, int n_in,
                              void* d_out, int out_size, void* d_ws, size_t ws_size,
                              hipStream_t stream) {
    const float* x  = (const float*)d_in[0];
    // d_in[1] = mask (deterministically causal; ignored)
    const float* Wq = (const float*)d_in[2];
    const float* Wk = (const float*)d_in[3];
    const float* Wv = (const float*)d_in[4];
    const float* Wo = (const float*)d_in[5];
    const float* Wg = (const float*)d_in[6];
    float* out = (float*)d_out;

    const size_t MB = 1ull << 20;
    char* p = (char*)d_ws;
    unsigned short* xb    = (unsigned short*)(p);            // 16 MB (dead after QKV GEMM)
    unsigned short* Ob    = xb;                              // alias: attn out (bf16)
    unsigned short* Wqkvt = (unsigned short*)(p + 16 * MB);  // 10 MB: [2560][2048]
    unsigned short* Wot   = (unsigned short*)(p + 26 * MB);  // 8 MB
    unsigned short* QKV   = (unsigned short*)(p + 34 * MB);  // 20 MB: [4096][2560]
    unsigned short* Vt    = (unsigned short*)(p + 54 * MB);  // 2 MB: [B][256][T]
    float*          Gb    = (float*)(p + 56 * MB);           // 256 KB
    const int BT = B_SZ * T_SZ;  // 4096

    // casts / weight transposes (Wq|Wk|Wv stacked into Wqkvt rows)
    f32_to_bf16_k<<<dim3(BT * C_SZ / 2048), 256, 0, stream>>>(x, xb);
    transpose_f32_bf16<<<dim3(64, 64), 256, 0, stream>>>(Wq, Wqkvt, C_SZ, HQ * D);
    transpose_f32_bf16<<<dim3(8, 64), 256, 0, stream>>>(Wk, Wqkvt + (size_t)(HQ * D) * C_SZ, C_SZ, HKV * D);
    transpose_f32_bf16<<<dim3(8, 64), 256, 0, stream>>>(Wv, Wqkvt + (size_t)(HQ * D + HKV * D) * C_SZ, C_SZ, HKV * D);
    transpose_f32_bf16<<<dim3(64, 64), 256, 0, stream>>>(Wo, Wot, HQ * D, C_SZ);

    // fused QKV projection (bf16 out): [4096,2048] @ [2048,2560]
    gemm_bt_bf16<<<dim3(QKVN / 128, BT / 128), 256, 0, stream>>>(
        xb, Wqkvt, nullptr, QKV, BT, QKVN, C_SZ, 1);

    // V^T per batch from fused QKV (col offset 2304, row stride 2560)
    transpose_bf16_str<<<dim3((HKV * D) / 32, T_SZ / 32, B_SZ), 256, 0, stream>>>(
        QKV + HQ * D + HKV * D, Vt, T_SZ, HKV * D, QKVN,
        (long long)T_SZ * QKVN, (long long)(HKV * D) * T_SZ);

    gates_kernel<<<dim3(BT), 64, 0, stream>>>(x, Wg, Gb);

    attn_mfma<<<dim3(B_SZ * HQ, T_SZ / 64), 256, 0, stream>>>(QKV, Vt, Gb, Ob);

    // out = Ob @ Wo (fp32 out)
    gemm_bt_bf16<<<dim3(C_SZ / 128, BT / 128), 256, 0, stream>>>(
        Ob, Wot, out, nullptr, BT, C_SZ, HQ * D, 0);
}

// Round 5
// 327.910 us; speedup vs baseline: 9.1237x; 1.1121x over previous
//
#include <hip/hip_runtime.h>
#include <hip/hip_bf16.h>
#include <math.h>

#define HQ 16
#define HKV 2
#define D 128
#define B_SZ 2
#define T_SZ 2048
#define C_SZ 2048
#define QKVN 2688   // HQ*D + 2*HKV*D + 128 (gate cols 2560-2575, pad 2576-2687)

typedef __attribute__((ext_vector_type(8))) short short8;
typedef __attribute__((ext_vector_type(4))) float floatx4;

static __device__ __forceinline__ float fexp2(float x) {
    return __builtin_amdgcn_exp2f(x);   // v_exp_f32 (D = 2^S0)
}

static __device__ __forceinline__ unsigned short f2b(float f) {
    union { float f; unsigned u; } x; x.f = f;
    return (unsigned short)((x.u + 0x7fffu + ((x.u >> 16) & 1u)) >> 16);
}

static __device__ __forceinline__ unsigned int pk2(float a, float b) {
    float2 t; t.x = a; t.y = b;
    __hip_bfloat162 h = __float22bfloat162_rn(t);
    return *(unsigned int*)&h;
}

// async global->LDS, 16B per lane; LDS dst = wave-uniform base + lane*16
static __device__ __forceinline__ void load_lds16(const void* g, void* l) {
    __builtin_amdgcn_global_load_lds(
        (const __attribute__((address_space(1))) void*)g,
        (__attribute__((address_space(3))) void*)l,
        16, 0, 0);
}

// ---------------------------------------------------------------------------
__global__ __launch_bounds__(256) void f32_to_bf16_k(
    const float* __restrict__ in, unsigned short* __restrict__ out)
{
    int i = (blockIdx.x * 256 + threadIdx.x) * 8;
    float4 a = *(const float4*)(in + i);
    float4 b = *(const float4*)(in + i + 4);
    ushort4 o0, o1;
    o0.x = f2b(a.x); o0.y = f2b(a.y); o0.z = f2b(a.z); o0.w = f2b(a.w);
    o1.x = f2b(b.x); o1.y = f2b(b.y); o1.z = f2b(b.z); o1.w = f2b(b.w);
    *(ushort4*)(out + i) = o0;
    *(ushort4*)(out + i + 4) = o1;
}

// ---------------------------------------------------------------------------
// W (R,Cc) fp32 row-major -> premul * W^T (Cc,R) bf16 row-major.
// grid (Cc/32, R/32)
// ---------------------------------------------------------------------------
__global__ __launch_bounds__(256) void transpose_f32_bf16(
    const float* __restrict__ in, unsigned short* __restrict__ out,
    int R, int Cc, float premul)
{
    __shared__ float t[32][33];
    const int bc = blockIdx.x * 32, br = blockIdx.y * 32;
    const int tid = threadIdx.x;
    const int r = tid >> 3, c4 = (tid & 7) * 4;
    float4 v = *(const float4*)(in + (size_t)(br + r) * Cc + bc + c4);
    t[r][c4 + 0] = v.x; t[r][c4 + 1] = v.y; t[r][c4 + 2] = v.z; t[r][c4 + 3] = v.w;
    __syncthreads();
    ushort4 o;
    o.x = f2b(t[c4 + 0][r] * premul); o.y = f2b(t[c4 + 1][r] * premul);
    o.z = f2b(t[c4 + 2][r] * premul); o.w = f2b(t[c4 + 3][r] * premul);
    *(ushort4*)(out + (size_t)(bc + r) * R + br + c4) = o;
}

// ---------------------------------------------------------------------------
// Wg (2048,16) fp32 -> log2e * Wg^T rows appended into Wqkvt at row 2560.
// ---------------------------------------------------------------------------
__global__ __launch_bounds__(256) void wg_transpose(
    const float* __restrict__ Wg, unsigned short* __restrict__ out, float premul)
{
    int k = blockIdx.x * 256 + threadIdx.x;
    const float4* wr = (const float4*)(Wg + (size_t)k * 16);
    float4 w0 = wr[0], w1 = wr[1], w2 = wr[2], w3 = wr[3];
    float w[16] = {w0.x, w0.y, w0.z, w0.w, w1.x, w1.y, w1.z, w1.w,
                   w2.x, w2.y, w2.z, w2.w, w3.x, w3.y, w3.z, w3.w};
    #pragma unroll
    for (int h = 0; h < 16; ++h)
        out[(size_t)h * C_SZ + k] = f2b(w[h] * premul);
}

// ---------------------------------------------------------------------------
// Strided bf16 transpose: in (bz, R, Cc) row-stride istr -> out (bz, Cc, R).
// ---------------------------------------------------------------------------
__global__ __launch_bounds__(256) void transpose_bf16_str(
    const unsigned short* __restrict__ in, unsigned short* __restrict__ out,
    int R, int Cc, int istr, long long ibstr, long long obstr)
{
    __shared__ unsigned short t[32][36];
    const int bz = blockIdx.z;
    const int bc = blockIdx.x * 32, br = blockIdx.y * 32;
    const int tid = threadIdx.x;
    const int r = tid >> 3, c4 = (tid & 7) * 4;
    ushort4 v = *(const ushort4*)(in + (size_t)bz * ibstr + (size_t)(br + r) * istr + bc + c4);
    t[r][c4 + 0] = v.x; t[r][c4 + 1] = v.y; t[r][c4 + 2] = v.z; t[r][c4 + 3] = v.w;
    __syncthreads();
    ushort4 o;
    o.x = t[c4 + 0][r]; o.y = t[c4 + 1][r]; o.z = t[c4 + 2][r]; o.w = t[c4 + 3][r];
    *(ushort4*)(out + (size_t)bz * obstr + (size_t)(bc + r) * R + br + c4) = o;
}

// ---------------------------------------------------------------------------
// bf16 MFMA GEMM (m97 structure): C[M,N] = A[M,K] @ Bt[N,K]^T.
// 128x128 tile, 256 thr, BK=32, XOR-swizzled 16B LDS blocks.
// ---------------------------------------------------------------------------
__global__ __launch_bounds__(256) void gemm_bt_bf16(
    const unsigned short* __restrict__ A, const unsigned short* __restrict__ Bt,
    float* __restrict__ Cf, unsigned short* __restrict__ Cb,
    int M, int N, int K, int out_bf16)
{
    __shared__ unsigned short As[128 * 32];
    __shared__ unsigned short Bs[128 * 32];
    const int tid = threadIdx.x;
    const int lane = tid & 63, wave = tid >> 6;
    const int l15 = lane & 15, quad = lane >> 4;
    const int wr = wave >> 1, wc = wave & 1;
    const int bm = blockIdx.y * 128, bn = blockIdx.x * 128;

    floatx4 zero = {0.f, 0.f, 0.f, 0.f};
    floatx4 acc[4][4];
    #pragma unroll
    for (int i = 0; i < 4; ++i)
        #pragma unroll
        for (int j = 0; j < 4; ++j) acc[i][j] = zero;

    int arow[2], acol[2];
    #pragma unroll
    for (int it = 0; it < 2; ++it) {
        int idx = it * 256 + tid;
        int row = idx >> 2, sb = idx & 3;
        int cb = sb ^ ((row >> 1) & 3);
        arow[it] = row; acol[it] = cb * 8;
    }
    const int sw = quad ^ ((l15 >> 1) & 3);

    for (int k0 = 0; k0 < K; k0 += 32) {
        __syncthreads();
        #pragma unroll
        for (int it = 0; it < 2; ++it) {
            load_lds16(A  + (size_t)(bm + arow[it]) * K + k0 + acol[it],
                       &As[(it * 256 + wave * 64) * 8]);
            load_lds16(Bt + (size_t)(bn + arow[it]) * K + k0 + acol[it],
                       &Bs[(it * 256 + wave * 64) * 8]);
        }
        __syncthreads();

        short8 af[4], bf[4];
        #pragma unroll
        for (int mt = 0; mt < 4; ++mt)
            af[mt] = *(const short8*)&As[((wr * 64 + mt * 16 + l15) * 4 + sw) * 8];
        #pragma unroll
        for (int nt = 0; nt < 4; ++nt)
            bf[nt] = *(const short8*)&Bs[((wc * 64 + nt * 16 + l15) * 4 + sw) * 8];
        #pragma unroll
        for (int mt = 0; mt < 4; ++mt)
            #pragma unroll
            for (int nt = 0; nt < 4; ++nt)
                acc[mt][nt] = __builtin_amdgcn_mfma_f32_16x16x32_bf16(
                    af[mt], bf[nt], acc[mt][nt], 0, 0, 0);
    }

    #pragma unroll
    for (int mt = 0; mt < 4; ++mt)
        #pragma unroll
        for (int nt = 0; nt < 4; ++nt)
            #pragma unroll
            for (int r = 0; r < 4; ++r) {
                int m = bm + wr * 64 + mt * 16 + quad * 4 + r;
                int n = bn + wc * 64 + nt * 16 + l15;
                if (out_bf16) Cb[(size_t)m * N + n] = f2b(acc[mt][nt][r]);
                else          Cf[(size_t)m * N + n] = acc[mt][nt][r];
            }
}

// ---------------------------------------------------------------------------
// MFMA flash attention, transposed (S^T = K Q^T, O^T = V^T P^T), FIXED-BIAS
// softmax: scale*log2e pre-folded into Wq, so P = exp2(sacc - 32); softmax
// shift-invariance makes this exact (no overflow: |sacc| << 104). No running
// max / alpha / O-rescale; l is lane-local, reduced once at the end.
// Gate logit read from fused QKV col 2560+h (already *log2e).
// ---------------------------------------------------------------------------
__global__ __launch_bounds__(256) void attn_mfma(
    const unsigned short* __restrict__ QKV, const unsigned short* __restrict__ Vt,
    unsigned short* __restrict__ Ob)
{
    __shared__ __align__(16) unsigned short SMEM[64 * 128 + 128 * 64 + 4 * 16 * 72];
    unsigned short* Ks = SMEM;                        // [key][d] swizzled 16B blocks
    unsigned short* Vs = SMEM + 64 * 128;             // [d][key] swizzled
    unsigned short* Ps = SMEM + 64 * 128 + 128 * 64;  // [wave][q=16][72]
    unsigned short* Lo = SMEM;                        // epilogue [64][136] (aliases Ks/Vs)

    const int bh = blockIdx.x;
    const int qt = (int)gridDim.y - 1 - (int)blockIdx.y;  // long blocks dispatch first
    const int b = bh >> 4, h = bh & 15, kvh = h >> 3;
    const int tid = threadIdx.x;
    const int lane = tid & 63, w = tid >> 6;
    const int l15 = lane & 15, quad = lane >> 4;
    const int q_local = w * 16 + l15;
    const float BIAS = 32.0f;

    // Q fragments (B-operand): q row = qt*64 + q_local, k = kd*32 + quad*8 + j
    short8 aq[4];
    {
        const unsigned short* qp = QKV + (size_t)(b * T_SZ + qt * 64 + q_local) * QKVN
                                       + h * D + quad * 8;
        #pragma unroll
        for (int kd = 0; kd < 4; ++kd) aq[kd] = *(const short8*)(qp + kd * 32);
    }

    // staging pointers (kt=0)
    const unsigned short* kg[4];
    const unsigned short* vg[4];
    #pragma unroll
    for (int it = 0; it < 4; ++it) {
        int Bi = it * 256 + tid;
        int kr = Bi >> 4, kc = ((Bi & 15) ^ (kr & 15)) * 8;
        kg[it] = QKV + (size_t)(b * T_SZ + kr) * QKVN + HQ * D + kvh * D + kc;
        int vr = Bi >> 3, vc = ((Bi & 7) ^ (vr & 7)) * 8;
        vg[it] = Vt + (size_t)((b * HKV + kvh) * D + vr) * T_SZ + vc;
    }

    floatx4 zero = {0.f, 0.f, 0.f, 0.f};
    floatx4 oacc[8];   // O^T tiles: row=d (dt*16+quad*4+r), col=q (l15)
    #pragma unroll
    for (int dt = 0; dt < 8; ++dt) oacc[dt] = zero;
    float l_part = 0.f;

    for (int kt = 0; kt <= qt; ++kt) {
        __syncthreads();
        #pragma unroll
        for (int it = 0; it < 4; ++it) {
            load_lds16(kg[it] + (size_t)kt * 64 * QKVN, &Ks[(it * 256 + w * 64) * 8]);
            load_lds16(vg[it] + kt * 64,                &Vs[(it * 256 + w * 64) * 8]);
        }
        __syncthreads();

        // S^T = K Q^T : row=key (4 tiles), col=q; sacc already in log2 units
        floatx4 sacc[4];
        #pragma unroll
        for (int nt = 0; nt < 4; ++nt) sacc[nt] = zero;
        #pragma unroll
        for (int kd = 0; kd < 4; ++kd)
            #pragma unroll
            for (int nt = 0; nt < 4; ++nt) {
                short8 ak = *(const short8*)&Ks[((nt * 16 + l15) * 16 + ((kd * 4 + quad) ^ l15)) * 8];
                sacc[nt] = __builtin_amdgcn_mfma_f32_16x16x32_bf16(ak, aq[kd], sacc[nt], 0, 0, 0);
            }

        // fixed-bias exp2, lane-local l accumulation, packed P^T write
        float p[4][4];
        if (kt == qt) {
            #pragma unroll
            for (int nt = 0; nt < 4; ++nt)
                #pragma unroll
                for (int r = 0; r < 4; ++r) {
                    float e = fexp2(sacc[nt][r] - BIAS);
                    p[nt][r] = (nt * 16 + quad * 4 + r > q_local) ? 0.f : e;
                }
        } else {
            #pragma unroll
            for (int nt = 0; nt < 4; ++nt)
                #pragma unroll
                for (int r = 0; r < 4; ++r)
                    p[nt][r] = fexp2(sacc[nt][r] - BIAS);
        }
        #pragma unroll
        for (int nt = 0; nt < 4; ++nt) {
            l_part += (p[nt][0] + p[nt][1]) + (p[nt][2] + p[nt][3]);
            uint2 pw;
            pw.x = pk2(p[nt][0], p[nt][1]);
            pw.y = pk2(p[nt][2], p[nt][3]);
            *(uint2*)&Ps[(w * 16 + l15) * 72 + nt * 16 + quad * 4] = pw;
        }

        // O^T += V^T P^T
        #pragma unroll
        for (int kk = 0; kk < 2; ++kk) {
            short8 bp = *(const short8*)&Ps[(w * 16 + l15) * 72 + kk * 32 + quad * 8];
            #pragma unroll
            for (int dt = 0; dt < 8; ++dt) {
                short8 av = *(const short8*)&Vs[((dt * 16 + l15) * 8 + ((kk * 4 + quad) ^ (l15 & 7))) * 8];
                oacc[dt] = __builtin_amdgcn_mfma_f32_16x16x32_bf16(av, bp, oacc[dt], 0, 0, 0);
            }
        }
    }

    // final l reduction (keys partitioned across quads)
    float l = l_part;
    l += __shfl_xor(l, 16);
    l += __shfl_xor(l, 32);

    // epilogue: gate (sigmoid of fused bf16 logit*log2e) + normalize,
    // transpose O^T -> O via LDS
    __syncthreads();   // Ks/Vs dead before Lo overwrite
    {
        int token = b * T_SZ + qt * 64 + q_local;
        unsigned short gl = QKV[(size_t)token * QKVN + HQ * D + HKV * D * 2 + h];
        union { unsigned u; float f; } gx; gx.u = ((unsigned)gl) << 16;
        float g = 1.0f / (1.0f + fexp2(-gx.f));
        float f = g / l;
        #pragma unroll
        for (int dt = 0; dt < 8; ++dt) {
            uint2 ov;
            ov.x = pk2(oacc[dt][0] * f, oacc[dt][1] * f);
            ov.y = pk2(oacc[dt][2] * f, oacc[dt][3] * f);
            *(uint2*)&Lo[(size_t)q_local * 136 + dt * 16 + quad * 4] = ov;
        }
    }
    __syncthreads();
    {
        int row = tid >> 2, c0 = (tid & 3) * 32;
        size_t tok = (size_t)(b * T_SZ + qt * 64 + row);
        unsigned short* op = Ob + tok * (HQ * D) + h * D + c0;
        const unsigned short* lp = &Lo[(size_t)row * 136 + c0];
        short8 v0 = *(const short8*)(lp + 0);
        short8 v1 = *(const short8*)(lp + 8);
        short8 v2 = *(const short8*)(lp + 16);
        short8 v3 = *(const short8*)(lp + 24);
        *(short8*)(op + 0)  = v0; *(short8*)(op + 8)  = v1;
        *(short8*)(op + 16) = v2; *(short8*)(op + 24) = v3;
    }
}

// ---------------------------------------------------------------------------
extern "C" void kernel_launch(void* const* d_in, const int* in_sizes, int n_in,
                              void* d_out, int out_size, void* d_ws, size_t ws_size,
                              hipStream_t stream) {
    const float* x  = (const float*)d_in[0];
    // d_in[1] = mask (deterministically causal; ignored)
    const float* Wq = (const float*)d_in[2];
    const float* Wk = (const float*)d_in[3];
    const float* Wv = (const float*)d_in[4];
    const float* Wo = (const float*)d_in[5];
    const float* Wg = (const float*)d_in[6];
    float* out = (float*)d_out;

    const size_t KB = 1ull << 10;
    char* p = (char*)d_ws;
    unsigned short* xb    = (unsigned short*)(p);                  // 16 MB (dead after QKV GEMM)
    unsigned short* Ob    = xb;                                    // alias: attn out (bf16)
    unsigned short* Wqkvt = (unsigned short*)(p + 16384 * KB);     // 10.5 MB: [2688][2048]
    unsigned short* Wot   = (unsigned short*)(p + 27136 * KB);     // 8 MB
    unsigned short* QKV   = (unsigned short*)(p + 35328 * KB);     // 21 MB: [4096][2688]
    unsigned short* Vt    = (unsigned short*)(p + 56832 * KB);     // 2 MB: [B][256][T]
    const int BT = B_SZ * T_SZ;  // 4096

    const float c_q = (float)(0.08838834764831845 * 1.4426950408889634);  // scale*log2e
    const float c_g = 1.4426950408889634f;                                 // log2e

    // casts / weight transposes (Wq|Wk|Wv|Wg stacked into Wqkvt rows)
    f32_to_bf16_k<<<dim3(BT * C_SZ / 2048), 256, 0, stream>>>(x, xb);
    transpose_f32_bf16<<<dim3(64, 64), 256, 0, stream>>>(Wq, Wqkvt, C_SZ, HQ * D, c_q);
    transpose_f32_bf16<<<dim3(8, 64), 256, 0, stream>>>(
        Wk, Wqkvt + (size_t)(HQ * D) * C_SZ, C_SZ, HKV * D, 1.0f);
    transpose_f32_bf16<<<dim3(8, 64), 256, 0, stream>>>(
        Wv, Wqkvt + (size_t)(HQ * D + HKV * D) * C_SZ, C_SZ, HKV * D, 1.0f);
    wg_transpose<<<dim3(8), 256, 0, stream>>>(
        Wg, Wqkvt + (size_t)(HQ * D + 2 * HKV * D) * C_SZ, c_g);
    transpose_f32_bf16<<<dim3(64, 64), 256, 0, stream>>>(Wo, Wot, HQ * D, C_SZ, 1.0f);

    // fused QKV+gate projection (bf16 out): [4096,2048] @ [2048,2688]
    gemm_bt_bf16<<<dim3(QKVN / 128, BT / 128), 256, 0, stream>>>(
        xb, Wqkvt, nullptr, QKV, BT, QKVN, C_SZ, 1);

    // V^T per batch from fused QKV (col offset 2304, row stride 2688)
    transpose_bf16_str<<<dim3((HKV * D) / 32, T_SZ / 32, B_SZ), 256, 0, stream>>>(
        QKV + HQ * D + HKV * D, Vt, T_SZ, HKV * D, QKVN,
        (long long)T_SZ * QKVN, (long long)(HKV * D) * T_SZ);

    attn_mfma<<<dim3(B_SZ * HQ, T_SZ / 64), 256, 0, stream>>>(QKV, Vt, Ob);

    // out = Ob @ Wo (fp32 out)
    gemm_bt_bf16<<<dim3(C_SZ / 128, BT / 128), 256, 0, stream>>>(
        Ob, Wot, out, nullptr, BT, C_SZ, HQ * D, 0);
}

// Round 6
// 314.195 us; speedup vs baseline: 9.5220x; 1.0437x over previous
//
#include <hip/hip_runtime.h>
#include <hip/hip_bf16.h>
#include <math.h>

#define HQ 16
#define HKV 2
#define D 128
#define B_SZ 2
#define T_SZ 2048
#define C_SZ 2048
#define QKVN 2688   // HQ*D + 2*HKV*D + 128 (gate cols 2560-2575, pad 2576-2687)

#define C_Q 0.12753102f   // (1/sqrt(128)) * log2(e)
#define C_G 1.44269504f   // log2(e)

typedef __attribute__((ext_vector_type(8))) short short8;
typedef __attribute__((ext_vector_type(4))) float floatx4;

static __device__ __forceinline__ float fexp2(float x) {
    return __builtin_amdgcn_exp2f(x);   // v_exp_f32 (D = 2^S0)
}

static __device__ __forceinline__ unsigned short f2b(float f) {
    union { float f; unsigned u; } x; x.f = f;
    return (unsigned short)((x.u + 0x7fffu + ((x.u >> 16) & 1u)) >> 16);
}

static __device__ __forceinline__ unsigned int pk2(float a, float b) {
    float2 t; t.x = a; t.y = b;
    __hip_bfloat162 h = __float22bfloat162_rn(t);
    return *(unsigned int*)&h;
}

// async global->LDS, 16B per lane; LDS dst = wave-uniform base + lane*16
static __device__ __forceinline__ void load_lds16(const void* g, void* l) {
    __builtin_amdgcn_global_load_lds(
        (const __attribute__((address_space(1))) void*)g,
        (__attribute__((address_space(3))) void*)l,
        16, 0, 0);
}

// ---------------------------------------------------------------------------
// Fused prep: x cast + Wq/Wk/Wv/Wo transposes + Wg transpose, one dispatch.
// Block ranges: [0,4096) x-cast | [4096,8192) Wq | [8192,8704) Wk |
// [8704,9216) Wv | [9216,13312) Wo | [13312,13320) Wg.
// ---------------------------------------------------------------------------
static __device__ __forceinline__ void tr32(
    const float* __restrict__ in, unsigned short* __restrict__ out,
    int R, int Cc, float premul, int bx, int by, float (*t)[33])
{
    const int bc = bx * 32, br = by * 32;
    const int tid = threadIdx.x;
    const int r = tid >> 3, c4 = (tid & 7) * 4;
    float4 v = *(const float4*)(in + (size_t)(br + r) * Cc + bc + c4);
    t[r][c4 + 0] = v.x; t[r][c4 + 1] = v.y; t[r][c4 + 2] = v.z; t[r][c4 + 3] = v.w;
    __syncthreads();
    ushort4 o;
    o.x = f2b(t[c4 + 0][r] * premul); o.y = f2b(t[c4 + 1][r] * premul);
    o.z = f2b(t[c4 + 2][r] * premul); o.w = f2b(t[c4 + 3][r] * premul);
    *(ushort4*)(out + (size_t)(bc + r) * R + br + c4) = o;
}

__global__ __launch_bounds__(256) void prep_kernel(
    const float* __restrict__ x,  const float* __restrict__ Wq,
    const float* __restrict__ Wk, const float* __restrict__ Wv,
    const float* __restrict__ Wo, const float* __restrict__ Wg,
    unsigned short* __restrict__ xb, unsigned short* __restrict__ Wqkvt,
    unsigned short* __restrict__ Wot)
{
    __shared__ float t[32][33];
    const int bid = blockIdx.x;
    const int tid = threadIdx.x;
    if (bid < 4096) {                       // x -> bf16
        int i = bid * 2048 + tid * 8;
        float4 a = *(const float4*)(x + i);
        float4 b = *(const float4*)(x + i + 4);
        ushort4 o0, o1;
        o0.x = f2b(a.x); o0.y = f2b(a.y); o0.z = f2b(a.z); o0.w = f2b(a.w);
        o1.x = f2b(b.x); o1.y = f2b(b.y); o1.z = f2b(b.z); o1.w = f2b(b.w);
        *(ushort4*)(xb + i) = o0;
        *(ushort4*)(xb + i + 4) = o1;
    } else if (bid < 8192) {                // Wq^T * (scale*log2e)
        int n = bid - 4096;
        tr32(Wq, Wqkvt, C_SZ, HQ * D, C_Q, n & 63, n >> 6, t);
    } else if (bid < 8704) {                // Wk^T
        int n = bid - 8192;
        tr32(Wk, Wqkvt + (size_t)(HQ * D) * C_SZ, C_SZ, HKV * D, 1.0f, n & 7, n >> 3, t);
    } else if (bid < 9216) {                // Wv^T
        int n = bid - 8704;
        tr32(Wv, Wqkvt + (size_t)(HQ * D + HKV * D) * C_SZ, C_SZ, HKV * D, 1.0f, n & 7, n >> 3, t);
    } else if (bid < 13312) {               // Wo^T
        int n = bid - 9216;
        tr32(Wo, Wot, HQ * D, C_SZ, 1.0f, n & 63, n >> 6, t);
    } else {                                // Wg^T * log2e
        int k = (bid - 13312) * 256 + tid;
        const float4* wr = (const float4*)(Wg + (size_t)k * 16);
        float4 w0 = wr[0], w1 = wr[1], w2 = wr[2], w3 = wr[3];
        float w[16] = {w0.x, w0.y, w0.z, w0.w, w1.x, w1.y, w1.z, w1.w,
                       w2.x, w2.y, w2.z, w2.w, w3.x, w3.y, w3.z, w3.w};
        unsigned short* out = Wqkvt + (size_t)(HQ * D + 2 * HKV * D) * C_SZ;
        #pragma unroll
        for (int h = 0; h < 16; ++h)
            out[(size_t)h * C_SZ + k] = f2b(w[h] * C_G);
    }
}

// ---------------------------------------------------------------------------
// bf16 MFMA GEMM (m97 structure): C[M,N] = A[M,K] @ Bt[N,K]^T.
// 128x128 tile, 256 thr, BK=32, XOR-swizzled 16B LDS blocks.
// If Vt != null, blocks with bn in {2304, 2432} (the V columns of the fused
// QKV GEMM) write their tile TRANSPOSED to Vt[b][n-2304][token] via LDS
// (two 64-row passes; LDS union stays ~17 KB) instead of row-major.
// ---------------------------------------------------------------------------
__global__ __launch_bounds__(256) void gemm_bt_bf16(
    const unsigned short* __restrict__ A, const unsigned short* __restrict__ Bt,
    float* __restrict__ Cf, unsigned short* __restrict__ Cb,
    unsigned short* __restrict__ Vt, int M, int N, int K, int out_bf16)
{
    __shared__ __align__(16) unsigned short SM[8448];  // As[4096] Bs[4096] | Ct[64][132]
    unsigned short* As = SM;
    unsigned short* Bs = SM + 4096;
    const int tid = threadIdx.x;
    const int lane = tid & 63, wave = tid >> 6;
    const int l15 = lane & 15, quad = lane >> 4;
    const int wr = wave >> 1, wc = wave & 1;
    const int bm = blockIdx.y * 128, bn = blockIdx.x * 128;

    floatx4 zero = {0.f, 0.f, 0.f, 0.f};
    floatx4 acc[4][4];
    #pragma unroll
    for (int i = 0; i < 4; ++i)
        #pragma unroll
        for (int j = 0; j < 4; ++j) acc[i][j] = zero;

    int arow[2], acol[2];
    #pragma unroll
    for (int it = 0; it < 2; ++it) {
        int idx = it * 256 + tid;
        int row = idx >> 2, sb = idx & 3;
        int cb = sb ^ ((row >> 1) & 3);
        arow[it] = row; acol[it] = cb * 8;
    }
    const int sw = quad ^ ((l15 >> 1) & 3);

    for (int k0 = 0; k0 < K; k0 += 32) {
        __syncthreads();
        #pragma unroll
        for (int it = 0; it < 2; ++it) {
            load_lds16(A  + (size_t)(bm + arow[it]) * K + k0 + acol[it],
                       &As[(it * 256 + wave * 64) * 8]);
            load_lds16(Bt + (size_t)(bn + arow[it]) * K + k0 + acol[it],
                       &Bs[(it * 256 + wave * 64) * 8]);
        }
        __syncthreads();

        short8 af[4], bf[4];
        #pragma unroll
        for (int mt = 0; mt < 4; ++mt)
            af[mt] = *(const short8*)&As[((wr * 64 + mt * 16 + l15) * 4 + sw) * 8];
        #pragma unroll
        for (int nt = 0; nt < 4; ++nt)
            bf[nt] = *(const short8*)&Bs[((wc * 64 + nt * 16 + l15) * 4 + sw) * 8];
        #pragma unroll
        for (int mt = 0; mt < 4; ++mt)
            #pragma unroll
            for (int nt = 0; nt < 4; ++nt)
                acc[mt][nt] = __builtin_amdgcn_mfma_f32_16x16x32_bf16(
                    af[mt], bf[nt], acc[mt][nt], 0, 0, 0);
    }

    if (Vt && (bn == 2304 || bn == 2432)) {
        // transposed epilogue: Vt[b][bn-2304 + n_local][token]
        unsigned short (*Ct)[132] = (unsigned short(*)[132])SM;
        const int bb = bm >> 11;            // token block's batch
        const int tl = bm & 2047;           // token local base
        #pragma unroll
        for (int vn = 0; vn < 2; ++vn) {
            __syncthreads();
            if (wc == vn) {
                #pragma unroll
                for (int mt = 0; mt < 4; ++mt)
                    #pragma unroll
                    for (int nt = 0; nt < 4; ++nt)
                        #pragma unroll
                        for (int r = 0; r < 4; ++r)
                            Ct[nt * 16 + l15][wr * 64 + mt * 16 + quad * 4 + r] =
                                f2b(acc[mt][nt][r]);
            }
            __syncthreads();
            int row = tid >> 2, cs = (tid & 3) * 32;
            int vrow = (bn - 2304) + vn * 64 + row;
            unsigned short* dst = Vt + ((size_t)bb * (HKV * D) + vrow) * T_SZ + tl + cs;
            const unsigned short* src = &Ct[row][cs];
            short8 v0 = *(const short8*)(src + 0);
            short8 v1 = *(const short8*)(src + 8);
            short8 v2 = *(const short8*)(src + 16);
            short8 v3 = *(const short8*)(src + 24);
            *(short8*)(dst + 0)  = v0; *(short8*)(dst + 8)  = v1;
            *(short8*)(dst + 16) = v2; *(short8*)(dst + 24) = v3;
        }
        return;
    }

    #pragma unroll
    for (int mt = 0; mt < 4; ++mt)
        #pragma unroll
        for (int nt = 0; nt < 4; ++nt)
            #pragma unroll
            for (int r = 0; r < 4; ++r) {
                int m = bm + wr * 64 + mt * 16 + quad * 4 + r;
                int n = bn + wc * 64 + nt * 16 + l15;
                if (out_bf16) Cb[(size_t)m * N + n] = f2b(acc[mt][nt][r]);
                else          Cf[(size_t)m * N + n] = acc[mt][nt][r];
            }
}

// ---------------------------------------------------------------------------
// MFMA flash attention, transposed (S^T = K Q^T, O^T = V^T P^T), fixed-bias
// softmax (scale*log2e folded into Wq; exact by shift-invariance).
// ---------------------------------------------------------------------------
__global__ __launch_bounds__(256) void attn_mfma(
    const unsigned short* __restrict__ QKV, const unsigned short* __restrict__ Vt,
    unsigned short* __restrict__ Ob)
{
    __shared__ __align__(16) unsigned short SMEM[64 * 128 + 128 * 64 + 4 * 16 * 72];
    unsigned short* Ks = SMEM;                        // [key][d] swizzled 16B blocks
    unsigned short* Vs = SMEM + 64 * 128;             // [d][key] swizzled
    unsigned short* Ps = SMEM + 64 * 128 + 128 * 64;  // [wave][q=16][72]
    unsigned short* Lo = SMEM;                        // epilogue [64][136] (aliases Ks/Vs)

    const int bh = blockIdx.x;
    const int qt = (int)gridDim.y - 1 - (int)blockIdx.y;  // long blocks dispatch first
    const int b = bh >> 4, h = bh & 15, kvh = h >> 3;
    const int tid = threadIdx.x;
    const int lane = tid & 63, w = tid >> 6;
    const int l15 = lane & 15, quad = lane >> 4;
    const int q_local = w * 16 + l15;
    const float BIAS = 32.0f;

    short8 aq[4];
    {
        const unsigned short* qp = QKV + (size_t)(b * T_SZ + qt * 64 + q_local) * QKVN
                                       + h * D + quad * 8;
        #pragma unroll
        for (int kd = 0; kd < 4; ++kd) aq[kd] = *(const short8*)(qp + kd * 32);
    }

    const unsigned short* kg[4];
    const unsigned short* vg[4];
    #pragma unroll
    for (int it = 0; it < 4; ++it) {
        int Bi = it * 256 + tid;
        int kr = Bi >> 4, kc = ((Bi & 15) ^ (kr & 15)) * 8;
        kg[it] = QKV + (size_t)(b * T_SZ + kr) * QKVN + HQ * D + kvh * D + kc;
        int vr = Bi >> 3, vc = ((Bi & 7) ^ (vr & 7)) * 8;
        vg[it] = Vt + (size_t)((b * HKV + kvh) * D + vr) * T_SZ + vc;
    }

    floatx4 zero = {0.f, 0.f, 0.f, 0.f};
    floatx4 oacc[8];   // O^T tiles: row=d (dt*16+quad*4+r), col=q (l15)
    #pragma unroll
    for (int dt = 0; dt < 8; ++dt) oacc[dt] = zero;
    float l_part = 0.f;

    for (int kt = 0; kt <= qt; ++kt) {
        __syncthreads();
        #pragma unroll
        for (int it = 0; it < 4; ++it) {
            load_lds16(kg[it] + (size_t)kt * 64 * QKVN, &Ks[(it * 256 + w * 64) * 8]);
            load_lds16(vg[it] + kt * 64,                &Vs[(it * 256 + w * 64) * 8]);
        }
        __syncthreads();

        floatx4 sacc[4];
        #pragma unroll
        for (int nt = 0; nt < 4; ++nt) sacc[nt] = zero;
        #pragma unroll
        for (int kd = 0; kd < 4; ++kd)
            #pragma unroll
            for (int nt = 0; nt < 4; ++nt) {
                short8 ak = *(const short8*)&Ks[((nt * 16 + l15) * 16 + ((kd * 4 + quad) ^ l15)) * 8];
                sacc[nt] = __builtin_amdgcn_mfma_f32_16x16x32_bf16(ak, aq[kd], sacc[nt], 0, 0, 0);
            }

        float p[4][4];
        if (kt == qt) {
            #pragma unroll
            for (int nt = 0; nt < 4; ++nt)
                #pragma unroll
                for (int r = 0; r < 4; ++r) {
                    float e = fexp2(sacc[nt][r] - BIAS);
                    p[nt][r] = (nt * 16 + quad * 4 + r > q_local) ? 0.f : e;
                }
        } else {
            #pragma unroll
            for (int nt = 0; nt < 4; ++nt)
                #pragma unroll
                for (int r = 0; r < 4; ++r)
                    p[nt][r] = fexp2(sacc[nt][r] - BIAS);
        }
        #pragma unroll
        for (int nt = 0; nt < 4; ++nt) {
            l_part += (p[nt][0] + p[nt][1]) + (p[nt][2] + p[nt][3]);
            uint2 pw;
            pw.x = pk2(p[nt][0], p[nt][1]);
            pw.y = pk2(p[nt][2], p[nt][3]);
            *(uint2*)&Ps[(w * 16 + l15) * 72 + nt * 16 + quad * 4] = pw;
        }

        #pragma unroll
        for (int kk = 0; kk < 2; ++kk) {
            short8 bp = *(const short8*)&Ps[(w * 16 + l15) * 72 + kk * 32 + quad * 8];
            #pragma unroll
            for (int dt = 0; dt < 8; ++dt) {
                short8 av = *(const short8*)&Vs[((dt * 16 + l15) * 8 + ((kk * 4 + quad) ^ (l15 & 7))) * 8];
                oacc[dt] = __builtin_amdgcn_mfma_f32_16x16x32_bf16(av, bp, oacc[dt], 0, 0, 0);
            }
        }
    }

    float l = l_part;
    l += __shfl_xor(l, 16);
    l += __shfl_xor(l, 32);

    __syncthreads();   // Ks/Vs dead before Lo overwrite
    {
        int token = b * T_SZ + qt * 64 + q_local;
        unsigned short gl = QKV[(size_t)token * QKVN + HQ * D + HKV * D * 2 + h];
        union { unsigned u; float f; } gx; gx.u = ((unsigned)gl) << 16;
        float g = 1.0f / (1.0f + fexp2(-gx.f));
        float f = g / l;
        #pragma unroll
        for (int dt = 0; dt < 8; ++dt) {
            uint2 ov;
            ov.x = pk2(oacc[dt][0] * f, oacc[dt][1] * f);
            ov.y = pk2(oacc[dt][2] * f, oacc[dt][3] * f);
            *(uint2*)&Lo[(size_t)q_local * 136 + dt * 16 + quad * 4] = ov;
        }
    }
    __syncthreads();
    {
        int row = tid >> 2, c0 = (tid & 3) * 32;
        size_t tok = (size_t)(b * T_SZ + qt * 64 + row);
        unsigned short* op = Ob + tok * (HQ * D) + h * D + c0;
        const unsigned short* lp = &Lo[(size_t)row * 136 + c0];
        short8 v0 = *(const short8*)(lp + 0);
        short8 v1 = *(const short8*)(lp + 8);
        short8 v2 = *(const short8*)(lp + 16);
        short8 v3 = *(const short8*)(lp + 24);
        *(short8*)(op + 0)  = v0; *(short8*)(op + 8)  = v1;
        *(short8*)(op + 16) = v2; *(short8*)(op + 24) = v3;
    }
}

// ---------------------------------------------------------------------------
extern "C" void kernel_launch(void* const* d_in, const int* in_sizes, int n_in,
                              void* d_out, int out_size, void* d_ws, size_t ws_size,
                              hipStream_t stream) {
    const float* x  = (const float*)d_in[0];
    // d_in[1] = mask (deterministically causal; ignored)
    const float* Wq = (const float*)d_in[2];
    const float* Wk = (const float*)d_in[3];
    const float* Wv = (const float*)d_in[4];
    const float* Wo = (const float*)d_in[5];
    const float* Wg = (const float*)d_in[6];
    float* out = (float*)d_out;

    const size_t KB = 1ull << 10;
    char* p = (char*)d_ws;
    unsigned short* xb    = (unsigned short*)(p);                  // 16 MB (dead after QKV GEMM)
    unsigned short* Ob    = xb;                                    // alias: attn out (bf16)
    unsigned short* Wqkvt = (unsigned short*)(p + 16384 * KB);     // 10.5 MB: [2688][2048]
    unsigned short* Wot   = (unsigned short*)(p + 27136 * KB);     // 8 MB
    unsigned short* QKV   = (unsigned short*)(p + 35328 * KB);     // 21 MB: [4096][2688]
    unsigned short* Vt    = (unsigned short*)(p + 56832 * KB);     // 2 MB: [B][256][T]
    const int BT = B_SZ * T_SZ;  // 4096

    // fused prep: x cast + all weight transposes (1 dispatch)
    prep_kernel<<<dim3(13320), 256, 0, stream>>>(x, Wq, Wk, Wv, Wo, Wg, xb, Wqkvt, Wot);

    // fused QKV+gate projection (bf16 out) with V^T epilogue fused
    gemm_bt_bf16<<<dim3(QKVN / 128, BT / 128), 256, 0, stream>>>(
        xb, Wqkvt, nullptr, QKV, Vt, BT, QKVN, C_SZ, 1);

    attn_mfma<<<dim3(B_SZ * HQ, T_SZ / 64), 256, 0, stream>>>(QKV, Vt, Ob);

    // out = Ob @ Wo (fp32 out)
    gemm_bt_bf16<<<dim3(C_SZ / 128, BT / 128), 256, 0, stream>>>(
        Ob, Wot, out, nullptr, nullptr, BT, C_SZ, HQ * D, 0);
}